// Round 6
// baseline (881.816 us; speedup 1.0000x reference)
//
#include <hip/hip_runtime.h>

// GraphSAGE 3-layer inference — R6.
//  * GEMM: small-tile / max-TLP. 64x64 block tile, 32x32 per wave, acc=16 VGPR,
//    ~100 VGPR total -> ~20 waves/CU. Latency hidden by wave count, not by
//    per-wave prefetch depth (R5 showed the compiler collapses register rings).
//  * A re-read per col-tile rides L3 (A is 102 MB, L3-resident).
//  * Layer 3 stays post-projection: T = [H@Ws3+b3 | H@Wn3], out = S + agg(P).

#define NN 100000
#define NE 800000
#define MPAD 100096   // 782 * 128 (multiple of 64)

typedef __attribute__((ext_vector_type(8))) short short8;
typedef __attribute__((ext_vector_type(4))) float floatx4;

__device__ __forceinline__ float bf2f(unsigned short u) {
    unsigned int x = ((unsigned int)u) << 16;
    return __builtin_bit_cast(float, x);
}
__device__ __forceinline__ unsigned short f2bf(float f) {
    unsigned int x = __builtin_bit_cast(unsigned int, f);
    x += 0x7fffu + ((x >> 16) & 1u);   // round-to-nearest-even
    return (unsigned short)(x >> 16);
}

// ---------------- CSR build ----------------
__global__ void degi_kernel(const int* __restrict__ dst, int* __restrict__ deg) {
    int e = blockIdx.x * blockDim.x + threadIdx.x;
    if (e < NE) atomicAdd(&deg[dst[e]], 1);
}

// Exclusive scan of 102400 ints (int4 per thread, 25 iterations).
__global__ __launch_bounds__(1024) void scan_kernel(const int4* __restrict__ deg4,
                                                    int4* __restrict__ cur4) {
    __shared__ int wsum[16];
    __shared__ int carry_s;
    const int tid = threadIdx.x, lane = tid & 63, w = tid >> 6;
    if (tid == 0) carry_s = 0;
    __syncthreads();
    for (int base = 0; base < 25600; base += 1024) {
        int i = base + tid;
        int4 v = deg4[i];
        int t = v.x + v.y + v.z + v.w;
        int s = t;
        #pragma unroll
        for (int off = 1; off < 64; off <<= 1) {
            int u = __shfl_up(s, off, 64);
            if (lane >= off) s += u;
        }
        if (lane == 63) wsum[w] = s;
        __syncthreads();
        if (w == 0) {
            int ws_ = (lane < 16) ? wsum[lane] : 0;
            int t2 = ws_;
            #pragma unroll
            for (int off = 1; off < 16; off <<= 1) {
                int u = __shfl_up(t2, off, 64);
                if (lane >= off) t2 += u;
            }
            if (lane < 16) wsum[lane] = t2 - ws_;
        }
        __syncthreads();
        int excl = carry_s + wsum[w] + (s - t);
        int4 o;
        o.x = excl; o.y = o.x + v.x; o.z = o.y + v.y; o.w = o.z + v.z;
        cur4[i] = o;
        __syncthreads();
        if (tid == 1023) carry_s = excl + t;
        __syncthreads();
    }
}

__global__ void scatter_kernel(const int* __restrict__ src, const int* __restrict__ dst,
                               int* __restrict__ cursor, int* __restrict__ nbr) {
    int e = blockIdx.x * blockDim.x + threadIdx.x;
    if (e < NE) {
        int pos = atomicAdd(&cursor[dst[e]], 1);
        nbr[pos] = src[e];
    }
}

// ---------------- casts / weight prep ----------------
__global__ void cast_x_kernel(const float4* __restrict__ x, unsigned short* __restrict__ H) {
    int gid = blockIdx.x * 256 + threadIdx.x;   // NN*64 float4 groups
    if (gid >= NN * 64) return;
    int row = gid >> 6, col = (gid & 63) * 4;
    float4 v = x[gid];
    ushort4 o;
    o.x = f2bf(v.x); o.y = f2bf(v.y); o.z = f2bf(v.z); o.w = f2bf(v.w);
    *(ushort4*)&H[(size_t)row * 512 + col] = o;
}

// Bt[n][k] = bf16( k<256 ? Ws[k][n] : Wn[k-256][n] ),  [256][512]
__global__ void wprep_kernel(const float* __restrict__ Ws, const float* __restrict__ Wn,
                             unsigned short* __restrict__ Bt) {
    int idx = blockIdx.x * 256 + threadIdx.x;
    if (idx >= 256 * 512) return;
    int n = idx >> 9, k = idx & 511;
    float v = (k < 256) ? Ws[(size_t)k * 256 + n] : Wn[(size_t)(k - 256) * 256 + n];
    Bt[idx] = f2bf(v);
}

// Bt3[n][k] (n<128, k<256): n<64 -> Ws3[k][n], else Wn3[k][n-64]; b3ext = [b3 | 0]
__global__ void wprep3_kernel(const float* __restrict__ Ws3, const float* __restrict__ Wn3,
                              const float* __restrict__ b3, unsigned short* __restrict__ Bt3,
                              float* __restrict__ b3ext) {
    int idx = blockIdx.x * 256 + threadIdx.x;
    if (idx < 128 * 256) {
        int n = idx >> 8, k = idx & 255;
        float v = (n < 64) ? Ws3[(size_t)k * 64 + n] : Wn3[(size_t)k * 64 + (n - 64)];
        Bt3[idx] = f2bf(v);
    }
    if (idx < 128) b3ext[idx] = (idx < 64) ? b3[idx] : 0.f;
}

// ---------------- pull-mean gather (bf16, half-wave per edge, 2x unroll) ----------------
__global__ __launch_bounds__(256) void gather_bf16(unsigned short* __restrict__ H,
                                                   const int* __restrict__ nbr,
                                                   const int* __restrict__ cursor,
                                                   const int* __restrict__ deg) {
    const int lane = threadIdx.x & 63;
    const int sub  = threadIdx.x >> 6;
    const int d = blockIdx.x * 4 + sub;
    if (d >= NN) return;
    const int dg = deg[d];
    const int end = cursor[d];
    const int start = end - dg;
    const int half = lane >> 5, l32 = lane & 31;
    float acc0[8] = {0.f, 0.f, 0.f, 0.f, 0.f, 0.f, 0.f, 0.f};
    float acc1[8] = {0.f, 0.f, 0.f, 0.f, 0.f, 0.f, 0.f, 0.f};
    int j = start + half;
    for (; j + 2 < end; j += 4) {
        int s0 = nbr[j], s1 = nbr[j + 2];
        short8 v0 = *(const short8*)&H[(size_t)s0 * 512 + l32 * 8];
        short8 v1 = *(const short8*)&H[(size_t)s1 * 512 + l32 * 8];
        #pragma unroll
        for (int i = 0; i < 8; ++i) acc0[i] += bf2f((unsigned short)v0[i]);
        #pragma unroll
        for (int i = 0; i < 8; ++i) acc1[i] += bf2f((unsigned short)v1[i]);
    }
    for (; j < end; j += 2) {
        int s0 = nbr[j];
        short8 v0 = *(const short8*)&H[(size_t)s0 * 512 + l32 * 8];
        #pragma unroll
        for (int i = 0; i < 8; ++i) acc0[i] += bf2f((unsigned short)v0[i]);
    }
    #pragma unroll
    for (int i = 0; i < 8; ++i) acc0[i] += acc1[i];
    #pragma unroll
    for (int i = 0; i < 8; ++i) acc0[i] += __shfl_xor(acc0[i], 32, 64);
    if (half == 0) {
        const float inv = 1.0f / fmaxf((float)dg, 1.0f);
        short8 o;
        #pragma unroll
        for (int i = 0; i < 8; ++i) o[i] = (short)f2bf(acc0[i] * inv);
        *(short8*)&H[(size_t)d * 512 + 256 + l32 * 8] = o;
    }
}

// ---------------- small-tile bf16 MFMA GEMM (max TLP) ----------------
// Block: 64x64 output tile, 4 waves in 2x2, each wave 32x32 (2x2 frags of
// 16x16x32). ~100 VGPR -> ~5 waves/SIMD. Latency hidden by occupancy.
// A row stride 512 (H fmt), Bt row stride KT*32. mfma(b,a): lane owns 4
// consecutive output cols.
template <int KT, bool RELU>
__global__ __launch_bounds__(256, 5) void sage_mfma(const unsigned short* __restrict__ A,
                                                    const unsigned short* __restrict__ Bt,
                                                    const float* __restrict__ bias,
                                                    unsigned short* __restrict__ Cout, int ldc) {
    __shared__ unsigned short slab[64 * 80];   // 80-short stride: 160B, 16B-aligned rows
    constexpr int BSTR = KT * 32;
    const int tid = threadIdx.x;
    const int lane = tid & 63;
    const int w = tid >> 6, wm = w >> 1, wn = w & 1;
    const int m0 = blockIdx.x * 64, n0 = blockIdx.y * 64;
    const int lr = lane & 15, lq = lane >> 4;

    const unsigned short* Ab = A  + (size_t)(m0 + wm * 32 + lr) * 512  + lq * 8;
    const unsigned short* Bb = Bt + (size_t)(n0 + wn * 32 + lr) * BSTR + lq * 8;

    floatx4 acc[2][2] = {};
    short8 a0[2], b0[2], a1[2], b1[2];

    auto load = [&](short8* a, short8* b, int kt) {
        #pragma unroll
        for (int mi = 0; mi < 2; ++mi) a[mi] = *(const short8*)(Ab + (size_t)mi * 16 * 512 + kt * 32);
        #pragma unroll
        for (int ni = 0; ni < 2; ++ni) b[ni] = *(const short8*)(Bb + (size_t)ni * 16 * BSTR + kt * 32);
    };
    auto compute = [&](short8* a, short8* b) {
        #pragma unroll
        for (int mi = 0; mi < 2; ++mi)
            #pragma unroll
            for (int ni = 0; ni < 2; ++ni)
                acc[mi][ni] = __builtin_amdgcn_mfma_f32_16x16x32_bf16(b[ni], a[mi],
                                                                      acc[mi][ni], 0, 0, 0);
    };

    load(a0, b0, 0);
    #pragma unroll
    for (int kt = 0; kt < KT; kt += 2) {
        if (kt + 1 < KT) load(a1, b1, kt + 1);
        compute(a0, b0);
        if (kt + 2 < KT) load(a0, b0, kt + 2);
        if (kt + 1 < KT) compute(a1, b1);
    }

    // Epilogue: bias + (relu) + bf16 -> LDS slab -> coalesced 16B stores.
    #pragma unroll
    for (int mi = 0; mi < 2; ++mi) {
        const int rl = wm * 32 + mi * 16 + lr;
        #pragma unroll
        for (int ni = 0; ni < 2; ++ni) {
            const int cl = wn * 32 + ni * 16 + lq * 4;
            const float4 bv = *(const float4*)&bias[n0 + cl];
            float v0 = acc[mi][ni][0] + bv.x;
            float v1 = acc[mi][ni][1] + bv.y;
            float v2 = acc[mi][ni][2] + bv.z;
            float v3 = acc[mi][ni][3] + bv.w;
            if (RELU) {
                v0 = fmaxf(v0, 0.f); v1 = fmaxf(v1, 0.f);
                v2 = fmaxf(v2, 0.f); v3 = fmaxf(v3, 0.f);
            }
            ushort4 o;
            o.x = f2bf(v0); o.y = f2bf(v1); o.z = f2bf(v2); o.w = f2bf(v3);
            *(ushort4*)&slab[rl * 80 + cl] = o;
        }
    }
    __syncthreads();
    #pragma unroll
    for (int it = 0; it < 2; ++it) {
        int idx = it * 256 + tid;          // 512 short8 chunks total
        int row = idx >> 3, c8 = (idx & 7) * 8;
        if (m0 + row < NN) {
            short8 v = *(const short8*)&slab[row * 80 + c8];
            *(short8*)&Cout[(size_t)(m0 + row) * ldc + n0 + c8] = v;
        }
    }
}

// ---------------- layer-3 finalize: out = S + mean_agg(P), 2x unroll ----------------
__global__ __launch_bounds__(256) void final_out(const unsigned short* __restrict__ T,
                                                 const int* __restrict__ nbr,
                                                 const int* __restrict__ cursor,
                                                 const int* __restrict__ deg,
                                                 float* __restrict__ out) {
    const int lane = threadIdx.x & 63;
    const int sub  = threadIdx.x >> 6;
    const int d = blockIdx.x * 4 + sub;
    if (d >= NN) return;
    const int dg = deg[d];
    const int end = cursor[d];
    float a0 = 0.f, a1 = 0.f;
    int j = end - dg;
    for (; j + 1 < end; j += 2) {
        int s0 = nbr[j], s1 = nbr[j + 1];
        float u0 = bf2f(T[(size_t)s0 * 128 + 64 + lane]);
        float u1 = bf2f(T[(size_t)s1 * 128 + 64 + lane]);
        a0 += u0; a1 += u1;
    }
    if (j < end) a0 += bf2f(T[(size_t)nbr[j] * 128 + 64 + lane]);
    const float inv = 1.0f / fmaxf((float)dg, 1.0f);
    const float sv = bf2f(T[(size_t)d * 128 + lane]);
    out[(size_t)d * 64 + lane] = sv + (a0 + a1) * inv;
}

extern "C" void kernel_launch(void* const* d_in, const int* in_sizes, int n_in,
                              void* d_out, int out_size, void* d_ws, size_t ws_size,
                              hipStream_t stream) {
    const float* x   = (const float*)d_in[0];
    const int*   src = (const int*)d_in[1];
    const int*   dst = (const int*)d_in[2];
    const float* Ws1 = (const float*)d_in[3];
    const float* Wn1 = (const float*)d_in[4];
    const float* b1  = (const float*)d_in[5];
    const float* Ws2 = (const float*)d_in[6];
    const float* Wn2 = (const float*)d_in[7];
    const float* b2  = (const float*)d_in[8];
    const float* Ws3 = (const float*)d_in[9];
    const float* Wn3 = (const float*)d_in[10];
    const float* b3  = (const float*)d_in[11];

    unsigned short* H1  = (unsigned short*)d_ws;
    unsigned short* H2  = H1  + (size_t)MPAD * 512;
    unsigned short* T   = H2  + (size_t)MPAD * 512;
    unsigned short* Bt1 = T   + (size_t)MPAD * 128;
    unsigned short* Bt2 = Bt1 + 256 * 512;
    unsigned short* Bt3 = Bt2 + 256 * 512;
    float* b3ext = (float*)(Bt3 + 128 * 256);
    int* deg    = (int*)(b3ext + 128);
    int* cursor = deg + 102400;
    int* nbr    = cursor + 102400;

    // CSR build (graph shared by all layers); pad region zeroed for int4 scan.
    hipMemsetAsync(deg, 0, 102400 * sizeof(int), stream);
    degi_kernel<<<(NE + 255) / 256, 256, 0, stream>>>(dst, deg);
    scan_kernel<<<1, 1024, 0, stream>>>((const int4*)deg, (int4*)cursor);
    scatter_kernel<<<(NE + 255) / 256, 256, 0, stream>>>(src, dst, cursor, nbr);
    // cursor[d] = end offset; bucket d = nbr[end-deg .. end)

    // bf16 prep
    cast_x_kernel<<<(NN * 64 + 255) / 256, 256, 0, stream>>>((const float4*)x, H1);
    wprep_kernel<<<512, 256, 0, stream>>>(Ws1, Wn1, Bt1);
    wprep_kernel<<<512, 256, 0, stream>>>(Ws2, Wn2, Bt2);
    wprep3_kernel<<<128, 256, 0, stream>>>(Ws3, Wn3, b3, Bt3, b3ext);

    const int gatherBlocks = (NN + 3) / 4;
    const dim3 g4(MPAD / 64, 4), g2(MPAD / 64, 2);

    // layer 1: H1 -> H2(left)
    gather_bf16<<<gatherBlocks, 256, 0, stream>>>(H1, nbr, cursor, deg);
    sage_mfma<16, true><<<g4, 256, 0, stream>>>(H1, Bt1, b1, H2, 512);

    // layer 2: H2 -> H1(left)
    gather_bf16<<<gatherBlocks, 256, 0, stream>>>(H2, nbr, cursor, deg);
    sage_mfma<16, true><<<g4, 256, 0, stream>>>(H2, Bt2, b2, H1, 512);

    // layer 3: T = [H1@Ws3+b3 | H1@Wn3] (K=256), then out = S + agg(P)
    sage_mfma<8, false><<<g2, 256, 0, stream>>>(H1, Bt3, b3ext, T, 128);
    final_out<<<gatherBlocks, 256, 0, stream>>>(T, nbr, cursor, deg, (float*)d_out);
}